// Round 7
// baseline (1711.103 us; speedup 1.0000x reference)
//
#include <hip/hip_runtime.h>

typedef short bf16x8 __attribute__((ext_vector_type(8)));
typedef unsigned short u16x8 __attribute__((ext_vector_type(8)));
typedef float f32x4 __attribute__((ext_vector_type(4)));

#define MFMA16(a, b, c) __builtin_amdgcn_mfma_f32_16x16x32_bf16((a), (b), (c), 0, 0, 0)

#define SCALEF 0.17677669529663687f  // 32^-0.5

__device__ __forceinline__ unsigned short f2bf(float f) {
  union { float f; unsigned u; } v; v.f = f;
  unsigned r = v.u + 0x7fffu + ((v.u >> 16) & 1u);  // RNE
  return (unsigned short)(r >> 16);
}
__device__ __forceinline__ float bf2f(unsigned short b) {
  union { unsigned u; float f; } v; v.u = ((unsigned)b) << 16;
  return v.f;
}

__device__ __forceinline__ void gl_lds16(const void* g, void* l) {
  __builtin_amdgcn_global_load_lds(
      (const __attribute__((address_space(1))) void*)g,
      (__attribute__((address_space(3))) void*)l, 16, 0, 0);
}

// ---------- prep kernels ----------
__global__ __launch_bounds__(256) void transpose_cvt_k(const float* __restrict__ W,
    unsigned short* __restrict__ Wt, int K, int N, float scale) {
  int i = blockIdx.x * 256 + threadIdx.x;
  if (i >= N * K) return;
  int n = i / K, k = i - n * K;
  Wt[i] = f2bf(W[(long)k * N + n] * scale);
}

__global__ __launch_bounds__(256) void scale_bias_k(const float* __restrict__ b,
    float* __restrict__ bs, float scale, int n) {
  int i = blockIdx.x * 256 + threadIdx.x;
  if (i < n) bs[i] = b[i] * scale;
}

// rpbp[h][q][lc*4+nt] = rpb[h][q][nt*16+lc]  (fragment-permuted, 256 KB f32)
__global__ __launch_bounds__(256) void build_rpbp_k(const float* __restrict__ bt,
    float* __restrict__ rpbp) {
  int i = blockIdx.x * 256 + threadIdx.x;
  if (i >= 16 * 64 * 64) return;
  int nt = i & 3, lcv = (i >> 2) & 15, q = (i >> 6) & 63, h = i >> 12;
  int k = nt * 16 + lcv;
  int dh = (q >> 3) - (k >> 3) + 7;
  int dw = (q & 7) - (k & 7) + 7;
  rpbp[i] = bt[(dh * 15 + dw) * 16 + h];
}

// fp32 -> bf16 bulk convert, 8 elems/thread
__global__ __launch_bounds__(256) void cvt_bf16_k(const float* __restrict__ in,
    unsigned short* __restrict__ out, int n8) {
  int i = blockIdx.x * 256 + threadIdx.x;
  if (i >= n8) return;
  const float4* p = (const float4*)(in + (size_t)i * 8);
  float4 a = p[0], b = p[1];
  uint4 pk;
  pk.x = (unsigned)f2bf(a.x) | ((unsigned)f2bf(a.y) << 16);
  pk.y = (unsigned)f2bf(a.z) | ((unsigned)f2bf(a.w) << 16);
  pk.z = (unsigned)f2bf(b.x) | ((unsigned)f2bf(b.y) << 16);
  pk.w = (unsigned)f2bf(b.z) | ((unsigned)f2bf(b.w) << 16);
  *(uint4*)(out + (size_t)i * 8) = pk;
}

// ---------- GEMM body (unchanged m97 structure) ----------
template <typename OT>
__device__ __forceinline__ void gemm_body(const unsigned short* __restrict__ A,
    const unsigned short* __restrict__ Bt, const float* __restrict__ bias,
    OT* __restrict__ C, int M, int N, int K)
{
  constexpr bool O_F32 = (sizeof(OT) == 4);

  __shared__ __align__(16) char smem[32768];
  unsigned short* Asm = (unsigned short*)smem;
  unsigned short* Bsm = Asm + 8192;

  const int tn = N >> 7;
  const int nbm = M >> 7;
  const int g = blockIdx.x;
  const int xcd = g & 7;
  const int s = g >> 3;
  const int bm = xcd * (nbm >> 3) + (s / tn);
  const int bn = s - (s / tn) * tn;

  const int tid = threadIdx.x;
  const int wave = tid >> 6, lane = tid & 63;
  const int wr = wave >> 1, wc = wave & 1;
  const int lg = lane >> 4, lc = lane & 15;

  const long rowBase = (long)bm * 128;
  const int colBase = bn * 128;
  const int KT = K >> 6;

  f32x4 acc[4][4];
#pragma unroll
  for (int i = 0; i < 4; ++i)
#pragma unroll
    for (int j = 0; j < 4; ++j)
      acc[i][j] = f32x4{0.f, 0.f, 0.f, 0.f};

  const int blr = lane >> 3;
  const int bsw = (lane & 7) ^ blr;

  auto issueA = [&](int kt) {
#pragma unroll
    for (int j = 0; j < 4; ++j) {
      int r = j * 32 + wave * 8 + blr;
      gl_lds16(A + (rowBase + r) * (long)K + kt * 64 + bsw * 8,
               Asm + (j * 4 + wave) * 512);
    }
  };
  auto issueB = [&](int kt) {
#pragma unroll
    for (int j = 0; j < 4; ++j) {
      int r = j * 32 + wave * 8 + blr;
      gl_lds16(Bt + (long)(colBase + r) * K + kt * 64 + bsw * 8,
               Bsm + (j * 4 + wave) * 512);
    }
  };
  auto compute = [&]() {
#pragma unroll
    for (int ks = 0; ks < 2; ++ks) {
      const int ca = (ks * 4 + lg) ^ (lc & 7);
      bf16x8 af[4], bfr[4];
#pragma unroll
      for (int mt = 0; mt < 4; ++mt)
        af[mt] = *(const bf16x8*)(Asm + (wr * 64 + mt * 16 + lc) * 64 + ca * 8);
#pragma unroll
      for (int nt = 0; nt < 4; ++nt)
        bfr[nt] = *(const bf16x8*)(Bsm + (wc * 64 + nt * 16 + lc) * 64 + ca * 8);
#pragma unroll
      for (int mt = 0; mt < 4; ++mt)
#pragma unroll
        for (int nt = 0; nt < 4; ++nt)
          acc[mt][nt] = MFMA16(af[mt], bfr[nt], acc[mt][nt]);
    }
  };

  issueA(0); issueB(0);
  __syncthreads();

  for (int kt = 0; kt < KT; ++kt) {
    const bool more = (kt + 1 < KT);
    compute();
    __syncthreads();
    if (more) {
      issueA(kt + 1); issueB(kt + 1);
      __syncthreads();
    }
  }

  float bv[4];
#pragma unroll
  for (int nt = 0; nt < 4; ++nt)
    bv[nt] = bias[colBase + wc * 64 + nt * 16 + lc];

  if constexpr (O_F32) {
    float* Sf = (float*)smem;
#pragma unroll
    for (int h = 0; h < 2; ++h) {
      if (wr == h) {
#pragma unroll
        for (int mt = 0; mt < 4; ++mt)
#pragma unroll
          for (int nt = 0; nt < 4; ++nt)
#pragma unroll
            for (int r = 0; r < 4; ++r)
              Sf[(mt * 16 + lg * 4 + r) * 128 + wc * 64 + nt * 16 + lc] =
                  acc[mt][nt][r] + bv[nt];
      }
      __syncthreads();
#pragma unroll
      for (int p = 0; p < 8; ++p) {
        int ch = p * 256 + tid, row = ch >> 5, c = ch & 31;
        *(float4*)((float*)C + (rowBase + h * 64 + row) * N + colBase + c * 4) =
            *(const float4*)(Sf + row * 128 + c * 4);
      }
      __syncthreads();
    }
  } else {
    unsigned short* Su = (unsigned short*)smem;
#pragma unroll
    for (int h = 0; h < 2; ++h) {
      if (wr == h) {
#pragma unroll
        for (int mt = 0; mt < 4; ++mt)
#pragma unroll
          for (int nt = 0; nt < 4; ++nt)
#pragma unroll
            for (int r = 0; r < 4; ++r)
              Su[(mt * 16 + lg * 4 + r) * 128 + wc * 64 + nt * 16 + lc] =
                  f2bf(acc[mt][nt][r] + bv[nt]);
      }
      __syncthreads();
#pragma unroll
      for (int p = 0; p < 4; ++p) {
        int ch = p * 256 + tid, row = ch >> 4, c = ch & 15;
        *(uint4*)((unsigned short*)C + (rowBase + h * 64 + row) * N + colBase + c * 8) =
            *(const uint4*)(Su + row * 128 + c * 8);
      }
      __syncthreads();
    }
  }
}

__global__ __launch_bounds__(256, 4) void gemm_q_k(const unsigned short* __restrict__ A,
    const unsigned short* __restrict__ Bt, const float* __restrict__ bias,
    unsigned short* __restrict__ C, int M, int N, int K) {
  gemm_body<unsigned short>(A, Bt, bias, C, M, N, K);
}
__global__ __launch_bounds__(256, 4) void gemm_kv_k(const unsigned short* __restrict__ A,
    const unsigned short* __restrict__ Bt, const float* __restrict__ bias,
    unsigned short* __restrict__ C, int M, int N, int K) {
  gemm_body<unsigned short>(A, Bt, bias, C, M, N, K);
}

// ---------- fused window attention + output projection ----------
// grid = 4096 windows, 4 waves. Wave w: heads 4w..4w+3 (phase 1) and output
// cols w*128..w*128+127 (phase 2). Per head-iter hi: waves produce x-chunk
// (64 q x 128 d, cols w*32.. per wave) in LDS, barrier, then all waves
// accumulate oacc += xchunk @ Wp[chunk rows] with Wp_t B-frags from L2.
// mask staged once per block in LDS (bf16, fragment-permuted); rpb from a
// 256 KB L2-hot permuted table. Scale pre-folded into Wq/bq.
__global__ __launch_bounds__(256, 2) void attn_out_k(
    const unsigned short* __restrict__ qh,   // [B*64][512] bf16
    const unsigned short* __restrict__ kvh,  // [B*64][1024] bf16 (k | v)
    const float* __restrict__ mask,          // [64][64][64] f32
    const float* __restrict__ rpbp,          // [16][64][64] f32 permuted
    const unsigned short* __restrict__ WpT,  // [512][512] bf16 (n,k)
    const float* __restrict__ bp,            // [512]
    float* __restrict__ out)                 // [B*64][512] f32
{
  __shared__ unsigned short P[4][64][68];    // 34816 B, per-wave probs
  __shared__ unsigned short Vt[4][32][68];   // 17408 B, per-wave V^T
  __shared__ unsigned short xc[64][136];     // 17408 B, shared x-chunk
  __shared__ unsigned short maskS[64][68];   //  8704 B, permuted bf16 mask

  const int b = blockIdx.x;
  const int w = b & 63;
  const int tid = threadIdx.x;
  const int wave = tid >> 6, lane = tid & 63;
  const int lg = lane >> 4, lc = lane & 15;
  const long rowQ = (long)b * 64;

  // stage mask (once per block): coalesced f32 reads, permuted bf16 writes
#pragma unroll
  for (int t = 0; t < 16; ++t) {
    int i = t * 256 + tid;                   // 4096 elems
    int q = i >> 6, k = i & 63;
    maskS[q][(k & 15) * 4 + (k >> 4)] = f2bf(mask[w * 4096 + i]);
  }

  f32x4 oacc[4][8];
#pragma unroll
  for (int i = 0; i < 4; ++i)
#pragma unroll
    for (int j = 0; j < 8; ++j)
      oacc[i][j] = f32x4{0.f, 0.f, 0.f, 0.f};

  __syncthreads();  // mask ready

  for (int hi = 0; hi < 4; ++hi) {
    const int h = wave * 4 + hi;

    // ---- phase 1: attention for head h ----
    u16x8 vr[4];
    {
      const unsigned short* vp = kvh + (rowQ + lane) * 1024 + 512 + h * 32;
      vr[0] = *(const u16x8*)(vp);
      vr[1] = *(const u16x8*)(vp + 8);
      vr[2] = *(const u16x8*)(vp + 16);
      vr[3] = *(const u16x8*)(vp + 24);
    }

    bf16x8 qf[4], kf[4];
#pragma unroll
    for (int mt = 0; mt < 4; ++mt)
      qf[mt] = *(const bf16x8*)(qh + (rowQ + mt * 16 + lc) * 512 + h * 32 + lg * 8);
#pragma unroll
    for (int nt = 0; nt < 4; ++nt)
      kf[nt] = *(const bf16x8*)(kvh + (rowQ + nt * 16 + lc) * 1024 + h * 32 + lg * 8);

    f32x4 acc[4][4];
#pragma unroll
    for (int mt = 0; mt < 4; ++mt)
#pragma unroll
      for (int nt = 0; nt < 4; ++nt)
        acc[mt][nt] = f32x4{0.f, 0.f, 0.f, 0.f};
#pragma unroll
    for (int mt = 0; mt < 4; ++mt)
#pragma unroll
      for (int nt = 0; nt < 4; ++nt)
        acc[mt][nt] = MFMA16(qf[mt], kf[nt], acc[mt][nt]);

    // softmax (scale folded into Wq/bq upstream)
    const float* rpq = rpbp + (h << 12) + lc * 4;
    float pden[4][4];
#pragma unroll
    for (int mt = 0; mt < 4; ++mt) {
#pragma unroll
      for (int r = 0; r < 4; ++r) {
        const int qrow = mt * 16 + lg * 4 + r;
        f32x4 rp = *(const f32x4*)(rpq + qrow * 64);
        ushort4 mv = *(const ushort4*)&maskS[qrow][lc * 4];
        float sc[4];
        sc[0] = acc[mt][0][r] + rp[0] + bf2f(mv.x);
        sc[1] = acc[mt][1][r] + rp[1] + bf2f(mv.y);
        sc[2] = acc[mt][2][r] + rp[2] + bf2f(mv.z);
        sc[3] = acc[mt][3][r] + rp[3] + bf2f(mv.w);
        float mx = fmaxf(fmaxf(sc[0], sc[1]), fmaxf(sc[2], sc[3]));
        mx = fmaxf(mx, __shfl_xor(mx, 1));
        mx = fmaxf(mx, __shfl_xor(mx, 2));
        mx = fmaxf(mx, __shfl_xor(mx, 4));
        mx = fmaxf(mx, __shfl_xor(mx, 8));
        float s = 0.f;
#pragma unroll
        for (int nt = 0; nt < 4; ++nt) { sc[nt] = __expf(sc[nt] - mx); s += sc[nt]; }
        s += __shfl_xor(s, 1);
        s += __shfl_xor(s, 2);
        s += __shfl_xor(s, 4);
        s += __shfl_xor(s, 8);
        pden[mt][r] = 1.f / s;
#pragma unroll
        for (int nt = 0; nt < 4; ++nt)
          P[wave][qrow][nt * 16 + lc] = f2bf(sc[nt]);
      }
    }

    // V^T scatter (vr returned under QK+softmax)
#pragma unroll
    for (int j = 0; j < 8; ++j) {
      Vt[wave][j][lane]      = vr[0][j];
      Vt[wave][8 + j][lane]  = vr[1][j];
      Vt[wave][16 + j][lane] = vr[2][j];
      Vt[wave][24 + j][lane] = vr[3][j];
    }

    // PV
    f32x4 xacc[4][2];
#pragma unroll
    for (int mt = 0; mt < 4; ++mt)
#pragma unroll
      for (int nt = 0; nt < 2; ++nt)
        xacc[mt][nt] = f32x4{0.f, 0.f, 0.f, 0.f};
#pragma unroll
    for (int ks = 0; ks < 2; ++ks) {
      bf16x8 pa[4], vb[2];
#pragma unroll
      for (int mt = 0; mt < 4; ++mt)
        pa[mt] = *(const bf16x8*)&P[wave][mt * 16 + lc][ks * 32 + lg * 8];
#pragma unroll
      for (int nt = 0; nt < 2; ++nt)
        vb[nt] = *(const bf16x8*)&Vt[wave][nt * 16 + lc][ks * 32 + lg * 8];
#pragma unroll
      for (int mt = 0; mt < 4; ++mt)
#pragma unroll
        for (int nt = 0; nt < 2; ++nt)
          xacc[mt][nt] = MFMA16(pa[mt], vb[nt], xacc[mt][nt]);
    }

    // normalized x-chunk -> LDS (wave's 32 cols)
#pragma unroll
    for (int mt = 0; mt < 4; ++mt)
#pragma unroll
      for (int nt = 0; nt < 2; ++nt)
#pragma unroll
        for (int r = 0; r < 4; ++r)
          xc[mt * 16 + lg * 4 + r][wave * 32 + nt * 16 + lc] =
              f2bf(xacc[mt][nt][r] * pden[mt][r]);

    __syncthreads();  // x-chunk complete

    // ---- phase 2: oacc += xchunk @ Wp[chunk rows] ----
    // chunk col cc maps to d = (4*(cc>>5) + hi)*32 + (cc&31)
#pragma unroll
    for (int kk = 0; kk < 4; ++kk) {
      const int dbase = (4 * kk + hi) * 32;
      bf16x8 af[4], bfr[8];
#pragma unroll
      for (int mt = 0; mt < 4; ++mt)
        af[mt] = *(const bf16x8*)&xc[mt * 16 + lc][kk * 32 + lg * 8];
#pragma unroll
      for (int nt = 0; nt < 8; ++nt)
        bfr[nt] = *(const bf16x8*)(WpT +
            (size_t)(wave * 128 + nt * 16 + lc) * 512 + dbase + lg * 8);
#pragma unroll
      for (int mt = 0; mt < 4; ++mt)
#pragma unroll
        for (int nt = 0; nt < 8; ++nt)
          oacc[mt][nt] = MFMA16(af[mt], bfr[nt], oacc[mt][nt]);
    }

    __syncthreads();  // xc consumed; next hi may overwrite
  }

  // epilogue: bias + direct f32 stores (16 lanes x 4B = full 64B sectors)
  float bv[8];
#pragma unroll
  for (int nt = 0; nt < 8; ++nt)
    bv[nt] = bp[wave * 128 + nt * 16 + lc];
#pragma unroll
  for (int mt = 0; mt < 4; ++mt)
#pragma unroll
    for (int nt = 0; nt < 8; ++nt)
#pragma unroll
      for (int r = 0; r < 4; ++r)
        out[(rowQ + mt * 16 + lg * 4 + r) * 512 + wave * 128 + nt * 16 + lc] =
            oacc[mt][nt][r] + bv[nt];
}

extern "C" void kernel_launch(void* const* d_in, const int* in_sizes, int n_in,
                              void* d_out, int out_size, void* d_ws, size_t ws_size,
                              hipStream_t stream) {
  const float* q    = (const float*)d_in[0];
  const float* kv   = (const float*)d_in[1];
  const float* mask = (const float*)d_in[2];
  const float* Wq   = (const float*)d_in[3];
  const float* bq   = (const float*)d_in[4];
  const float* Wkv  = (const float*)d_in[5];
  const float* bkv  = (const float*)d_in[6];
  const float* btab = (const float*)d_in[7];
  const float* Wp   = (const float*)d_in[8];
  const float* bp   = (const float*)d_in[9];
  float* out = (float*)d_out;

  const int M = 4096 * 64;  // 262144 rows

  char* ws = (char*)d_ws;
  const size_t OFF_QH   = 0;                               // 256 MB
  const size_t OFF_KVH  = OFF_QH + (size_t)M * 512 * 2;    // 512 MB
  const size_t OFF_SCR  = OFF_KVH + (size_t)M * 1024 * 2;  // 256 MB (kvbf -> qbf)
  const size_t OFF_WQT  = OFF_SCR + (size_t)M * 512 * 2;
  const size_t OFF_WKVT = OFF_WQT + 512 * 512 * 2;
  const size_t OFF_WPT  = OFF_WKVT + 1024 * 512 * 2;
  const size_t OFF_RPBP = OFF_WPT + 512 * 512 * 2;         // 256 KB
  const size_t OFF_BQS  = OFF_RPBP + 16 * 64 * 64 * 4;     // 2 KB

  unsigned short* qh    = (unsigned short*)(ws + OFF_QH);
  unsigned short* kvh   = (unsigned short*)(ws + OFF_KVH);
  unsigned short* scr   = (unsigned short*)(ws + OFF_SCR);
  unsigned short* Wq_t  = (unsigned short*)(ws + OFF_WQT);
  unsigned short* Wkv_t = (unsigned short*)(ws + OFF_WKVT);
  unsigned short* Wp_t  = (unsigned short*)(ws + OFF_WPT);
  float* rpbp           = (float*)(ws + OFF_RPBP);
  float* bq_s           = (float*)(ws + OFF_BQS);

  transpose_cvt_k<<<(512 * 512 + 255) / 256, 256, 0, stream>>>(Wq, Wq_t, 512, 512, SCALEF);
  transpose_cvt_k<<<(512 * 1024 + 255) / 256, 256, 0, stream>>>(Wkv, Wkv_t, 512, 1024, 1.0f);
  transpose_cvt_k<<<(512 * 512 + 255) / 256, 256, 0, stream>>>(Wp, Wp_t, 512, 512, 1.0f);
  scale_bias_k<<<2, 256, 0, stream>>>(bq, bq_s, SCALEF, 512);
  build_rpbp_k<<<(16 * 64 * 64) / 256, 256, 0, stream>>>(btab, rpbp);

  const int n8 = M * 512 / 8;

  cvt_bf16_k<<<n8 / 256, 256, 0, stream>>>(kv, scr, n8);
  gemm_kv_k<<<(M / 128) * (1024 / 128), 256, 0, stream>>>(scr, Wkv_t, bkv, kvh, M, 1024, 512);

  cvt_bf16_k<<<n8 / 256, 256, 0, stream>>>(q, scr, n8);
  gemm_q_k<<<(M / 128) * (512 / 128), 256, 0, stream>>>(scr, Wq_t, bq_s, qh, M, 512, 512);

  attn_out_k<<<4096, 256, 0, stream>>>(qh, kvh, mask, rpbp, Wp_t, bp, out);

  (void)in_sizes; (void)n_in; (void)out_size; (void)ws_size;
}

// Round 8
// 1381.200 us; speedup vs baseline: 1.2389x; 1.2389x over previous
//
#include <hip/hip_runtime.h>

typedef short bf16x8 __attribute__((ext_vector_type(8)));
typedef unsigned short u16x8 __attribute__((ext_vector_type(8)));
typedef float f32x4 __attribute__((ext_vector_type(4)));

#define MFMA16(a, b, c) __builtin_amdgcn_mfma_f32_16x16x32_bf16((a), (b), (c), 0, 0, 0)

#define SCALEF 0.17677669529663687f  // 32^-0.5

__device__ __forceinline__ unsigned short f2bf(float f) {
  union { float f; unsigned u; } v; v.f = f;
  unsigned r = v.u + 0x7fffu + ((v.u >> 16) & 1u);  // RNE
  return (unsigned short)(r >> 16);
}
__device__ __forceinline__ float bf2f(unsigned short b) {
  union { unsigned u; float f; } v; v.u = ((unsigned)b) << 16;
  return v.f;
}

__device__ __forceinline__ void gl_lds16(const void* g, void* l) {
  __builtin_amdgcn_global_load_lds(
      (const __attribute__((address_space(1))) void*)g,
      (__attribute__((address_space(3))) void*)l, 16, 0, 0);
}

// ---------- prep kernels ----------
__global__ __launch_bounds__(256) void transpose_cvt_k(const float* __restrict__ W,
    unsigned short* __restrict__ Wt, int K, int N, float scale) {
  int i = blockIdx.x * 256 + threadIdx.x;
  if (i >= N * K) return;
  int n = i / K, k = i - n * K;
  Wt[i] = f2bf(W[(long)k * N + n] * scale);
}

__global__ __launch_bounds__(256) void scale_bias_k(const float* __restrict__ b,
    float* __restrict__ bs, float scale, int n) {
  int i = blockIdx.x * 256 + threadIdx.x;
  if (i < n) bs[i] = b[i] * scale;
}

// rpbp[h][q][lc*4+kt] = rpb[h][q][kt*16+lc]  (fragment-permuted, 256 KB f32)
__global__ __launch_bounds__(256) void build_rpbp_k(const float* __restrict__ bt,
    float* __restrict__ rpbp) {
  int i = blockIdx.x * 256 + threadIdx.x;
  if (i >= 16 * 64 * 64) return;
  int kt = i & 3, lcv = (i >> 2) & 15, q = (i >> 6) & 63, h = i >> 12;
  int k = kt * 16 + lcv;
  int dh = (q >> 3) - (k >> 3) + 7;
  int dw = (q & 7) - (k & 7) + 7;
  rpbp[i] = bt[(dh * 15 + dw) * 16 + h];
}

// fp32 -> bf16 bulk convert, 8 elems/thread
__global__ __launch_bounds__(256) void cvt_bf16_k(const float* __restrict__ in,
    unsigned short* __restrict__ out, int n8) {
  int i = blockIdx.x * 256 + threadIdx.x;
  if (i >= n8) return;
  const float4* p = (const float4*)(in + (size_t)i * 8);
  float4 a = p[0], b = p[1];
  uint4 pk;
  pk.x = (unsigned)f2bf(a.x) | ((unsigned)f2bf(a.y) << 16);
  pk.y = (unsigned)f2bf(a.z) | ((unsigned)f2bf(a.w) << 16);
  pk.z = (unsigned)f2bf(b.x) | ((unsigned)f2bf(b.y) << 16);
  pk.w = (unsigned)f2bf(b.z) | ((unsigned)f2bf(b.w) << 16);
  *(uint4*)(out + (size_t)i * 8) = pk;
}

// ---------- GEMM body (m97 structure, proven) ----------
template <typename OT>
__device__ __forceinline__ void gemm_body(const unsigned short* __restrict__ A,
    const unsigned short* __restrict__ Bt, const float* __restrict__ bias,
    OT* __restrict__ C, int M, int N, int K)
{
  constexpr bool O_F32 = (sizeof(OT) == 4);

  __shared__ __align__(16) char smem[32768];
  unsigned short* Asm = (unsigned short*)smem;
  unsigned short* Bsm = Asm + 8192;

  const int tn = N >> 7;
  const int nbm = M >> 7;
  const int g = blockIdx.x;
  const int xcd = g & 7;
  const int s = g >> 3;
  const int bm = xcd * (nbm >> 3) + (s / tn);
  const int bn = s - (s / tn) * tn;

  const int tid = threadIdx.x;
  const int wave = tid >> 6, lane = tid & 63;
  const int wr = wave >> 1, wc = wave & 1;
  const int lg = lane >> 4, lc = lane & 15;

  const long rowBase = (long)bm * 128;
  const int colBase = bn * 128;
  const int KT = K >> 6;

  f32x4 acc[4][4];
#pragma unroll
  for (int i = 0; i < 4; ++i)
#pragma unroll
    for (int j = 0; j < 4; ++j)
      acc[i][j] = f32x4{0.f, 0.f, 0.f, 0.f};

  const int blr = lane >> 3;
  const int bsw = (lane & 7) ^ blr;

  auto issueA = [&](int kt) {
#pragma unroll
    for (int j = 0; j < 4; ++j) {
      int r = j * 32 + wave * 8 + blr;
      gl_lds16(A + (rowBase + r) * (long)K + kt * 64 + bsw * 8,
               Asm + (j * 4 + wave) * 512);
    }
  };
  auto issueB = [&](int kt) {
#pragma unroll
    for (int j = 0; j < 4; ++j) {
      int r = j * 32 + wave * 8 + blr;
      gl_lds16(Bt + (long)(colBase + r) * K + kt * 64 + bsw * 8,
               Bsm + (j * 4 + wave) * 512);
    }
  };
  auto compute = [&]() {
#pragma unroll
    for (int ks = 0; ks < 2; ++ks) {
      const int ca = (ks * 4 + lg) ^ (lc & 7);
      bf16x8 af[4], bfr[4];
#pragma unroll
      for (int mt = 0; mt < 4; ++mt)
        af[mt] = *(const bf16x8*)(Asm + (wr * 64 + mt * 16 + lc) * 64 + ca * 8);
#pragma unroll
      for (int nt = 0; nt < 4; ++nt)
        bfr[nt] = *(const bf16x8*)(Bsm + (wc * 64 + nt * 16 + lc) * 64 + ca * 8);
#pragma unroll
      for (int mt = 0; mt < 4; ++mt)
#pragma unroll
        for (int nt = 0; nt < 4; ++nt)
          acc[mt][nt] = MFMA16(af[mt], bfr[nt], acc[mt][nt]);
    }
  };

  issueA(0); issueB(0);
  __syncthreads();

  for (int kt = 0; kt < KT; ++kt) {
    const bool more = (kt + 1 < KT);
    compute();
    __syncthreads();
    if (more) {
      issueA(kt + 1); issueB(kt + 1);
      __syncthreads();
    }
  }

  float bv[4];
#pragma unroll
  for (int nt = 0; nt < 4; ++nt)
    bv[nt] = bias[colBase + wc * 64 + nt * 16 + lc];

  if constexpr (O_F32) {
    float* Sf = (float*)smem;
#pragma unroll
    for (int h = 0; h < 2; ++h) {
      if (wr == h) {
#pragma unroll
        for (int mt = 0; mt < 4; ++mt)
#pragma unroll
          for (int nt = 0; nt < 4; ++nt)
#pragma unroll
            for (int r = 0; r < 4; ++r)
              Sf[(mt * 16 + lg * 4 + r) * 128 + wc * 64 + nt * 16 + lc] =
                  acc[mt][nt][r] + bv[nt];
      }
      __syncthreads();
#pragma unroll
      for (int p = 0; p < 8; ++p) {
        int ch = p * 256 + tid, row = ch >> 5, c = ch & 31;
        *(float4*)((float*)C + (rowBase + h * 64 + row) * N + colBase + c * 4) =
            *(const float4*)(Sf + row * 128 + c * 4);
      }
      __syncthreads();
    }
  } else {
    unsigned short* Su = (unsigned short*)smem;
#pragma unroll
    for (int h = 0; h < 2; ++h) {
      if (wr == h) {
#pragma unroll
        for (int mt = 0; mt < 4; ++mt)
#pragma unroll
          for (int nt = 0; nt < 4; ++nt)
#pragma unroll
            for (int r = 0; r < 4; ++r)
              Su[(mt * 16 + lg * 4 + r) * 128 + wc * 64 + nt * 16 + lc] =
                  f2bf(acc[mt][nt][r] + bv[nt]);
      }
      __syncthreads();
#pragma unroll
      for (int p = 0; p < 4; ++p) {
        int ch = p * 256 + tid, row = ch >> 4, c = ch & 15;
        *(uint4*)((unsigned short*)C + (rowBase + h * 64 + row) * N + colBase + c * 8) =
            *(const uint4*)(Su + row * 128 + c * 8);
      }
      __syncthreads();
    }
  }
}

__global__ __launch_bounds__(256, 4) void gemm_q_k(const unsigned short* __restrict__ A,
    const unsigned short* __restrict__ Bt, const float* __restrict__ bias,
    unsigned short* __restrict__ C, int M, int N, int K) {
  gemm_body<unsigned short>(A, Bt, bias, C, M, N, K);
}
__global__ __launch_bounds__(256, 4) void gemm_kv_k(const unsigned short* __restrict__ A,
    const unsigned short* __restrict__ Bt, const float* __restrict__ bias,
    unsigned short* __restrict__ C, int M, int N, int K) {
  gemm_body<unsigned short>(A, Bt, bias, C, M, N, K);
}
__global__ __launch_bounds__(256, 4) void gemm_out_k(const unsigned short* __restrict__ A,
    const unsigned short* __restrict__ Bt, const float* __restrict__ bias,
    float* __restrict__ C, int M, int N, int K) {
  gemm_body<float>(A, Bt, bias, C, M, N, K);
}

// ---------- fused window attention, head-cooperative ----------
// grid = 4096 windows, 4 waves. All 4 waves work on ONE head at a time
// (16 heads sequential, 1 barrier/head): wave w owns q-rows w*16..w*16+15.
// V^T staged cooperatively (256 threads), double-buffered, prefetched 1 head
// ahead. Per wave per head: 1 Q-frag, 4 K-frags, 4 QK MFMA, 4-row softmax,
// 4 PV MFMA. Output staged via xs for full-sector 64B stores.
// LDS 31232 B -> 5 blocks/CU (20 waves/CU).
__global__ __launch_bounds__(256, 5) void attn_k(
    const unsigned short* __restrict__ qh,   // [B*64][512] bf16
    const unsigned short* __restrict__ kvh,  // [B*64][1024] bf16 (k | v)
    const float* __restrict__ mask,          // [64][64][64] f32
    const float* __restrict__ rpbp,          // [16][64][64] f32 permuted
    unsigned short* __restrict__ x)          // [B*64][512] bf16
{
  __shared__ unsigned short P[64][68];       // 8704 B (wave w: rows w*16..)
  __shared__ unsigned short Vt[2][32][68];   // 8704 B, double-buffered V^T
  __shared__ unsigned short maskS[64][68];   // 8704 B, permuted bf16 mask
  __shared__ unsigned short xs[4][16][40];   // 5120 B, out-staging

  const int b = blockIdx.x;
  const int w = b & 63;
  const int tid = threadIdx.x;
  const int wave = tid >> 6, lane = tid & 63;
  const int lg = lane >> 4, lc = lane & 15;
  const long rowQ = (long)b * 64;

  // stage mask once (permuted: col = (k&15)*4 + (k>>4))
#pragma unroll
  for (int t = 0; t < 16; ++t) {
    int i = t * 256 + tid;
    int qq = i >> 6, k = i & 63;
    maskS[qq][(k & 15) * 4 + (k >> 4)] = f2bf(mask[w * 4096 + i]);
  }

  // V staging geometry: thread -> (token = tid>>2, d-group = tid&3)
  const int vtok = tid >> 2, vg = tid & 3;
  const unsigned short* vbase = kvh + (rowQ + vtok) * 1024 + 512 + vg * 8;

  // stage V[head 0] into buf 0
  {
    u16x8 v0 = *(const u16x8*)(vbase);
#pragma unroll
    for (int j = 0; j < 8; ++j) Vt[0][vg * 8 + j][vtok] = v0[j];
  }
  __syncthreads();

  for (int h = 0; h < 16; ++h) {
    const int cur = h & 1;

    // prefetch next head's V slice into regs (hidden under QK+softmax)
    u16x8 vn;
    if (h < 15) vn = *(const u16x8*)(vbase + (h + 1) * 32);

    // Q frag (wave's 16 rows) + K frags (all 64 tokens, L1-shared)
    bf16x8 qf = *(const bf16x8*)(qh + (rowQ + wave * 16 + lc) * 512 + h * 32 + lg * 8);
    bf16x8 kf[4];
#pragma unroll
    for (int kt = 0; kt < 4; ++kt)
      kf[kt] = *(const bf16x8*)(kvh + (rowQ + kt * 16 + lc) * 1024 + h * 32 + lg * 8);

    f32x4 acc[4];
#pragma unroll
    for (int kt = 0; kt < 4; ++kt) acc[kt] = f32x4{0.f, 0.f, 0.f, 0.f};
#pragma unroll
    for (int kt = 0; kt < 4; ++kt) acc[kt] = MFMA16(qf, kf[kt], acc[kt]);

    // softmax: lane handles rows q = wave*16 + lg*4 + r
    float pden[4];
#pragma unroll
    for (int r = 0; r < 4; ++r) {
      const int qrow = wave * 16 + lg * 4 + r;
      f32x4 rp = *(const f32x4*)(rpbp + (h << 12) + qrow * 64 + lc * 4);
      ushort4 mv = *(const ushort4*)&maskS[qrow][lc * 4];
      float sc[4];
      sc[0] = acc[0][r] + rp[0] + bf2f(mv.x);
      sc[1] = acc[1][r] + rp[1] + bf2f(mv.y);
      sc[2] = acc[2][r] + rp[2] + bf2f(mv.z);
      sc[3] = acc[3][r] + rp[3] + bf2f(mv.w);
      float mx = fmaxf(fmaxf(sc[0], sc[1]), fmaxf(sc[2], sc[3]));
      mx = fmaxf(mx, __shfl_xor(mx, 1));
      mx = fmaxf(mx, __shfl_xor(mx, 2));
      mx = fmaxf(mx, __shfl_xor(mx, 4));
      mx = fmaxf(mx, __shfl_xor(mx, 8));
      float s = 0.f;
#pragma unroll
      for (int kt = 0; kt < 4; ++kt) { sc[kt] = __expf(sc[kt] - mx); s += sc[kt]; }
      s += __shfl_xor(s, 1);
      s += __shfl_xor(s, 2);
      s += __shfl_xor(s, 4);
      s += __shfl_xor(s, 8);
      pden[r] = 1.f / s;
#pragma unroll
      for (int kt = 0; kt < 4; ++kt)
        P[qrow][kt * 16 + lc] = f2bf(sc[kt]);
    }

    // write next head's V^T into the other buffer (readers finished last iter)
    if (h < 15) {
#pragma unroll
      for (int j = 0; j < 8; ++j) Vt[cur ^ 1][vg * 8 + j][vtok] = vn[j];
    }

    // PV: out[q][d] for wave's rows; P rows are wave-private (no barrier)
    f32x4 xacc[2];
    xacc[0] = f32x4{0.f, 0.f, 0.f, 0.f};
    xacc[1] = f32x4{0.f, 0.f, 0.f, 0.f};
#pragma unroll
    for (int ks = 0; ks < 2; ++ks) {
      bf16x8 pa = *(const bf16x8*)&P[wave * 16 + lc][ks * 32 + lg * 8];
      bf16x8 vb0 = *(const bf16x8*)&Vt[cur][lc][ks * 32 + lg * 8];
      bf16x8 vb1 = *(const bf16x8*)&Vt[cur][16 + lc][ks * 32 + lg * 8];
      xacc[0] = MFMA16(pa, vb0, xacc[0]);
      xacc[1] = MFMA16(pa, vb1, xacc[1]);
    }

    // normalize -> xs -> full-sector 64B stores
#pragma unroll
    for (int dt = 0; dt < 2; ++dt)
#pragma unroll
      for (int r = 0; r < 4; ++r)
        xs[wave][lg * 4 + r][dt * 16 + lc] = f2bf(xacc[dt][r] * pden[r]);
    {
      int row = lane >> 2, c = lane & 3;
      uint4 v = *(const uint4*)&xs[wave][row][c * 8];
      *(uint4*)(x + (rowQ + wave * 16 + row) * 512 + h * 32 + c * 8) = v;
    }

    __syncthreads();  // Vt[cur] readers done before iter h+1 writes it
  }
}

extern "C" void kernel_launch(void* const* d_in, const int* in_sizes, int n_in,
                              void* d_out, int out_size, void* d_ws, size_t ws_size,
                              hipStream_t stream) {
  const float* q    = (const float*)d_in[0];
  const float* kv   = (const float*)d_in[1];
  const float* mask = (const float*)d_in[2];
  const float* Wq   = (const float*)d_in[3];
  const float* bq   = (const float*)d_in[4];
  const float* Wkv  = (const float*)d_in[5];
  const float* bkv  = (const float*)d_in[6];
  const float* btab = (const float*)d_in[7];
  const float* Wp   = (const float*)d_in[8];
  const float* bp   = (const float*)d_in[9];
  float* out = (float*)d_out;

  const int M = 4096 * 64;  // 262144 rows

  char* ws = (char*)d_ws;
  const size_t OFF_QH   = 0;                               // 256 MB
  const size_t OFF_KVH  = OFF_QH + (size_t)M * 512 * 2;    // 512 MB
  const size_t OFF_SCR  = OFF_KVH + (size_t)M * 1024 * 2;  // 256 MB time-shared
  const size_t OFF_WQT  = OFF_SCR + (size_t)M * 512 * 2;
  const size_t OFF_WKVT = OFF_WQT + 512 * 512 * 2;
  const size_t OFF_WPT  = OFF_WKVT + 1024 * 512 * 2;
  const size_t OFF_RPBP = OFF_WPT + 512 * 512 * 2;         // 256 KB
  const size_t OFF_BQS  = OFF_RPBP + 16 * 64 * 64 * 4;     // 2 KB

  unsigned short* qh    = (unsigned short*)(ws + OFF_QH);
  unsigned short* kvh   = (unsigned short*)(ws + OFF_KVH);
  unsigned short* scr   = (unsigned short*)(ws + OFF_SCR); // kvbf -> qbf -> xb
  unsigned short* Wq_t  = (unsigned short*)(ws + OFF_WQT);
  unsigned short* Wkv_t = (unsigned short*)(ws + OFF_WKVT);
  unsigned short* Wp_t  = (unsigned short*)(ws + OFF_WPT);
  float* rpbp           = (float*)(ws + OFF_RPBP);
  float* bq_s           = (float*)(ws + OFF_BQS);

  transpose_cvt_k<<<(512 * 512 + 255) / 256, 256, 0, stream>>>(Wq, Wq_t, 512, 512, SCALEF);
  transpose_cvt_k<<<(512 * 1024 + 255) / 256, 256, 0, stream>>>(Wkv, Wkv_t, 512, 1024, 1.0f);
  transpose_cvt_k<<<(512 * 512 + 255) / 256, 256, 0, stream>>>(Wp, Wp_t, 512, 512, 1.0f);
  scale_bias_k<<<2, 256, 0, stream>>>(bq, bq_s, SCALEF, 512);
  build_rpbp_k<<<(16 * 64 * 64) / 256, 256, 0, stream>>>(btab, rpbp);

  const int n8 = M * 512 / 8;

  cvt_bf16_k<<<n8 / 256, 256, 0, stream>>>(kv, scr, n8);
  gemm_kv_k<<<(M / 128) * (1024 / 128), 256, 0, stream>>>(scr, Wkv_t, bkv, kvh, M, 1024, 512);

  cvt_bf16_k<<<n8 / 256, 256, 0, stream>>>(q, scr, n8);
  gemm_q_k<<<(M / 128) * (512 / 128), 256, 0, stream>>>(scr, Wq_t, bq_s, qh, M, 512, 512);

  attn_k<<<4096, 256, 0, stream>>>(qh, kvh, mask, rpbp, scr);

  gemm_out_k<<<(M / 128) * (512 / 128), 256, 0, stream>>>(scr, Wp_t, bp, out, M, 512, 512);

  (void)in_sizes; (void)n_in; (void)out_size; (void)ws_size;
}